// Round 7
// baseline (1425.420 us; speedup 1.0000x reference)
//
#include <hip/hip_runtime.h>
#include <math.h>

#define B_    32
#define H_    32
#define KVH_  8
#define D_    128
#define HID_  4096
#define TPB_  64
#define MB_   32
#define G_    4
#define RQKV  6144
#define KS_   16
#define NCH   32
#define SCALING 0.08838834764831845f
#define AREP  8
#define GRPP  24
#define RREP  64

typedef __attribute__((ext_vector_type(8))) short short8_t;
typedef __attribute__((ext_vector_type(16))) float f32x16;

__device__ __forceinline__ unsigned int pk2(float lo, float hi) {
  return (__float_as_uint(hi) & 0xffff0000u) | (__float_as_uint(lo) >> 16);
}

__device__ __forceinline__ void gl_lds16(const void* g, void* l) {
  __builtin_amdgcn_global_load_lds((const __attribute__((address_space(1))) void*)g,
                                   (__attribute__((address_space(3))) void*)l, 16, 0, 0);
}

// ---------- build X B-fragments from hidden_q (int [32][4096]) ----------
__global__ __launch_bounds__(256) void kprep_x(const int* __restrict__ src, uint4* __restrict__ frag) {
  int gid = blockIdx.x * 256 + threadIdx.x;
  int l = gid & 63, t = gid >> 6;
  int bb = l & 31;
  int k0 = t * 16 + (l >> 5) * 8;
  const int* p = &src[(size_t)bb * HID_ + k0];
  int4 a = *(const int4*)p;
  int4 c = *(const int4*)(p + 4);
  uint4 o;
  o.x = pk2((float)a.x, (float)a.y);
  o.y = pk2((float)a.z, (float)a.w);
  o.z = pk2((float)c.x, (float)c.y);
  o.w = pk2((float)c.z, (float)c.w);
  frag[gid] = o;
}

// ---------- MFMA GEMM with LDS-staged W (REP: diagnostic amplification, pointer-opaque) ----------
template <int REP>
__global__ __launch_bounds__(256) void kgemm_mfma(const int* __restrict__ W, const uint4* __restrict__ xf,
                                                  float* __restrict__ Yp, int R) {
  __shared__ __align__(16) int wtile[8192];
  int tid = threadIdx.x;
  int wave = tid >> 6, lane = tid & 63;
  int j0 = blockIdx.x * 128;
  int row = lane & 31, hi = lane >> 5;
  int kbase = blockIdx.y * 256;
  uint4 bw[16];
#pragma unroll
  for (int t = 0; t < 16; t++) bw[t] = xf[(size_t)((kbase >> 4) + t) * 64 + lane];
  int ldsrow = wave * 32 + row;
  int rsw = ldsrow & 7;
  const int* Wb = W + (size_t)j0 * HID_ + kbase;
  for (int rep = 0; rep < REP; rep++) {
    asm volatile("" : "+v"(Wb) :: "memory");
    f32x16 acc;
#pragma unroll
    for (int i = 0; i < 16; i++) acc[i] = 0.f;
    for (int ss = 0; ss < 4; ss++) {
#pragma unroll
      for (int n = 0; n < 8; n++) {
        int f = n * 4096 + tid * 16;
        int r = f >> 8;
        int sl = (f >> 4) & 15;
        const int* gsrc = Wb + (size_t)r * HID_ + ss * 64 + ((sl ^ (r & 7)) << 2);
        gl_lds16(gsrc, (char*)wtile + f);
      }
      __syncthreads();
#pragma unroll
      for (int t = 0; t < 4; t++) {
        int s0 = 4 * t + 2 * hi;
        int4 wa = *(const int4*)&wtile[ldsrow * 64 + ((s0 ^ rsw) << 2)];
        int4 wb = *(const int4*)&wtile[ldsrow * 64 + (((s0 + 1) ^ rsw) << 2)];
        uint4 aw;
        aw.x = pk2((float)wa.x, (float)wa.y);
        aw.y = pk2((float)wa.z, (float)wa.w);
        aw.z = pk2((float)wb.x, (float)wb.y);
        aw.w = pk2((float)wb.z, (float)wb.w);
        acc = __builtin_amdgcn_mfma_f32_32x32x16_bf16(__builtin_bit_cast(short8_t, aw),
                                                      __builtin_bit_cast(short8_t, bw[ss * 4 + t]),
                                                      acc, 0, 0, 0);
      }
      __syncthreads();
    }
    int jw = j0 + wave * 32;
#pragma unroll
    for (int r = 0; r < 16; r++) {
      int rowout = (r & 3) + 8 * (r >> 2) + 4 * hi;
      Yp[((size_t)blockIdx.y * R + jw + rowout) * 32 + (lane & 31)] = acc[r];
    }
  }
}

// ---------- coalesced reduce + LDS transpose (REP: diagnostic amplification) ----------
template <int REP>
__global__ __launch_bounds__(256) void kred(const float* __restrict__ Yp, const float* __restrict__ sb,
                                            const float* __restrict__ sj, float* __restrict__ outT, int R) {
  int tid = threadIdx.x;
  int j0 = blockIdx.x * 32;
  __shared__ float lds[32 * 33];
  const float* Ypv = Yp;
  for (int rep = 0; rep < REP; rep++) {
    asm volatile("" : "+v"(Ypv) :: "memory");
    float acc[4] = {0.f, 0.f, 0.f, 0.f};
    for (int ks = 0; ks < KS_; ks++) {
      const float* p = &Ypv[(size_t)ks * R * 32 + j0 * 32];
#pragma unroll
      for (int e = 0; e < 4; e++) acc[e] += p[e * 256 + tid];
    }
#pragma unroll
    for (int e = 0; e < 4; e++) {
      int f = e * 256 + tid;
      int jl = f >> 5, b = f & 31;
      lds[b * 33 + jl] = acc[e];
    }
    __syncthreads();
#pragma unroll
    for (int e = 0; e < 4; e++) {
      int f = e * 256 + tid;
      int b = f >> 5, jl = f & 31;
      outT[(size_t)b * R + j0 + jl] = lds[b * 33 + jl] * sb[b] * sj[j0 + jl];
    }
    __syncthreads();
  }
}

// ---------- RoPE + fresh k/v quant ----------
__global__ __launch_bounds__(128) void kpost_qkv(const float* __restrict__ YsT, const int* __restrict__ ctx,
                                                 float* __restrict__ qrope, int* __restrict__ kqf,
                                                 int* __restrict__ vqf, float* __restrict__ ksf,
                                                 float* __restrict__ vsf) {
  int r = blockIdx.x;
  int b = blockIdx.y;
  int d = threadIdx.x;
  float v = YsT[(size_t)b * RQKV + r * 128 + d];
  __shared__ float x[128];
  __shared__ float red[2];
  x[d] = v;
  __syncthreads();
  int pos = ctx[b];
  float val;
  if (r < 40) {
    int i = d & 63;
    float f = powf(10000.f, -(float)i * (1.f / 64.f));
    float ang = (float)pos * f;
    float sv, cv;
    sincosf(ang, &sv, &cv);
    float xa = x[i], xb = x[i + 64];
    val = (d < 64) ? (xa * cv - xb * sv) : (xb * cv + xa * sv);
  } else {
    val = v;
  }
  if (r < 32) { qrope[((size_t)b * H_ + r) * D_ + d] = val; return; }
  float a = fabsf(val);
#pragma unroll
  for (int off = 32; off; off >>= 1) a = fmaxf(a, __shfl_xor(a, off));
  if ((d & 63) == 0) red[d >> 6] = a;
  __syncthreads();
  float mx = fmaxf(red[0], red[1]);
  float sc = fmaxf(mx, 1e-6f) * (1.f / 127.f);
  float qv = rintf(val / sc);
  qv = fminf(fmaxf(qv, -127.f), 127.f);
  int kvh = (r - 32) & 7;
  if (r < 40) {
    kqf[((size_t)b * KVH_ + kvh) * D_ + d] = (int)qv;
    if (d == 0) ksf[b * KVH_ + kvh] = sc;
  } else {
    vqf[((size_t)b * KVH_ + kvh) * D_ + d] = (int)qv;
    if (d == 0) vsf[b * KVH_ + kvh] = sc;
  }
}

// ---------- attention (AREP: diagnostic amplification) ----------
__global__ __launch_bounds__(256) void kattn(const int* __restrict__ kvc, const float* __restrict__ kvs,
                                             const int* __restrict__ btab, const int* __restrict__ ctx,
                                             const float* __restrict__ qrope, const int* __restrict__ kqf,
                                             const float* __restrict__ ksf,
                                             const int* __restrict__ vqf, const float* __restrict__ vsf,
                                             float* __restrict__ pm, float* __restrict__ pl,
                                             float* __restrict__ pacc) {
  int cb = blockIdx.x, kvh = blockIdx.y, b = blockIdx.z;
  int tid = threadIdx.x;
  int pos = ctx[b];
  size_t pbase = ((size_t)(b * KVH_ + kvh) * NCH + cb) * G_;
  if (cb * 64 > pos) {
    if (tid < 4) { pm[pbase + tid] = -1e30f; pl[pbase + tid] = 0.f; }
    return;
  }
  __shared__ __align__(16) int kint[8192];
  __shared__ __align__(16) float qlds[512];
  __shared__ float sls[4][64];
  __shared__ float pls[4][64];
  __shared__ float hb[4][128];
  int blk = btab[b * MB_ + cb];
  int freshT = pos - cb * 64;
  const int* kpan = &kvc[(((size_t)(blk * 2 + 0) * KVH_ + kvh) * TPB_) * D_];

#pragma unroll
  for (int n = 0; n < 8; n++) {
    int f = n * 4096 + tid * 16;
    int t = f >> 9;
    int sl = (f >> 4) & 31;
    const int* gsrc = kpan + t * 128 + ((sl ^ (t & 7)) << 2);
    gl_lds16(gsrc, (char*)kint + f);
  }
  for (int i = tid; i < 512; i += 256) {
    int sw = i ^ (((i >> 5) & 3) << 2);
    qlds[sw] = qrope[((size_t)b * H_ + kvh * G_) * D_ + i];
  }
  __syncthreads();

  for (int rep = 0; rep < AREP; rep++) {
    // ---- phase 1: QK^T, 4 lanes per token, K from LDS ----
    {
      int t = tid >> 2, c = tid & 3;
      int tsw = t & 7;
      float kv[32];
#pragma unroll
      for (int i = 0; i < 8; i++) {
        int4 k4 = *(const int4*)&kint[t * 128 + (((c * 8 + i) ^ tsw) << 2)];
        kv[i * 4 + 0] = (float)k4.x;
        kv[i * 4 + 1] = (float)k4.y;
        kv[i * 4 + 2] = (float)k4.z;
        kv[i * 4 + 3] = (float)k4.w;
      }
      float ksc = kvs[((size_t)(blk * 2 + 0) * KVH_ + kvh) * TPB_ + t] * SCALING;
#pragma unroll
      for (int g = 0; g < 4; g++) {
        int base = g * 128 + c * 32;
        float dot = 0.f;
#pragma unroll
        for (int i = 0; i < 8; i++) {
          float4 q4 = *(const float4*)&qlds[(base + i * 4) ^ (c << 2)];
          dot += kv[i * 4 + 0] * q4.x + kv[i * 4 + 1] * q4.y +
                 kv[i * 4 + 2] * q4.z + kv[i * 4 + 3] * q4.w;
        }
        dot += __shfl_xor(dot, 1);
        dot += __shfl_xor(dot, 2);
        if (c == 0) sls[g][t] = dot * ksc;
      }
    }
    __syncthreads();

    // ---- phase 2: softmax ----
    {
      int g = tid >> 6, t = tid & 63;
      int s = cb * 64 + t;
      float sc = sls[g][t];
      if (freshT >= 0 && freshT < 64) {
        const int* kk = &kqf[(size_t)(b * KVH_ + kvh) * D_];
        float q1 = qlds[(g * 128 + t) ^ (((t >> 5) & 3) << 2)];
        float q2 = qlds[(g * 128 + 64 + t) ^ ((((t >> 5) + 2) & 3) << 2)];
        float dotf = q1 * (float)kk[t] + q2 * (float)kk[t + 64];
#pragma unroll
        for (int off = 32; off; off >>= 1) dotf += __shfl_xor(dotf, off);
        if (t == freshT) sc = dotf * ksf[b * KVH_ + kvh] * SCALING;
      }
      if (s > pos) sc = -1e30f;
      float m = sc;
#pragma unroll
      for (int off = 32; off; off >>= 1) m = fmaxf(m, __shfl_xor(m, off));
      float p = (s <= pos) ? expf(sc - m) : 0.f;
      float l = p;
#pragma unroll
      for (int off = 32; off; off >>= 1) l += __shfl_xor(l, off);
      if (t == 0) { pm[pbase + g] = m; pl[pbase + g] = l; }
      float vsc = (s == pos) ? vsf[b * KVH_ + kvh]
                             : kvs[((size_t)(blk * 2 + 1) * KVH_ + kvh) * TPB_ + t];
      pls[g][t] = p * vsc;
    }
    __syncthreads();

    // ---- phase 3: PV ----
    {
      int d = tid & 127, half = tid >> 7;
      const int* vbase = &kvc[(((size_t)(blk * 2 + 1) * KVH_ + kvh) * TPB_) * D_ + d];
      float a0 = 0.f, a1 = 0.f, a2 = 0.f, a3 = 0.f;
      for (int tt = half; tt < 64; tt += 2) {
        const int* vr = (tt == freshT) ? &vqf[(size_t)(b * KVH_ + kvh) * D_ + d] : vbase + tt * D_;
        float vv = (float)*vr;
        a0 = fmaf(pls[0][tt], vv, a0);
        a1 = fmaf(pls[1][tt], vv, a1);
        a2 = fmaf(pls[2][tt], vv, a2);
        a3 = fmaf(pls[3][tt], vv, a3);
      }
      __syncthreads();
      if (half == 1) { hb[0][d] = a0; hb[1][d] = a1; hb[2][d] = a2; hb[3][d] = a3; }
      __syncthreads();
      if (half == 0) {
        float* pa = &pacc[pbase * D_];
        pa[0 * D_ + d] = a0 + hb[0][d];
        pa[1 * D_ + d] = a1 + hb[1][d];
        pa[2 * D_ + d] = a2 + hb[2][d];
        pa[3 * D_ + d] = a3 + hb[3][d];
      }
    }
    asm volatile("" ::: "memory");
    __syncthreads();
  }
}

// ---------- combine chunks -> attnB[b][j] + partial amax ----------
__global__ __launch_bounds__(256) void kcomb1(const float* __restrict__ pm, const float* __restrict__ pl,
                                              const float* __restrict__ pacc, float* __restrict__ attnB,
                                              float* __restrict__ amaxp) {
  int sl = blockIdx.x, b = blockIdx.y;
  int tid = threadIdx.x;
  __shared__ float wch[32][32];
  __shared__ float invL[32];
  __shared__ float rbuf[4];
  if (tid < 32) {
    int kvh = tid >> 2, g = tid & 3;
    float M = -1e30f;
    float m[NCH];
#pragma unroll
    for (int ch = 0; ch < NCH; ch++) {
      m[ch] = pm[((size_t)(b * KVH_ + kvh) * NCH + ch) * G_ + g];
      M = fmaxf(M, m[ch]);
    }
    float L = 0.f;
#pragma unroll
    for (int ch = 0; ch < NCH; ch++) {
      float w = expf(m[ch] - M);
      wch[tid][ch] = w;
      L += pl[((size_t)(b * KVH_ + kvh) * NCH + ch) * G_ + g] * w;
    }
    invL[tid] = 1.f / L;
  }
  __syncthreads();
  float amax = 0.f;
#pragma unroll
  for (int rep = 0; rep < 2; rep++) {
    int j = sl * 512 + rep * 256 + tid;
    int h = j >> 7, d = j & 127;
    int kvh = h >> 2, g = h & 3;
    int hh = kvh * 4 + g;
    float v = 0.f;
#pragma unroll 8
    for (int ch = 0; ch < NCH; ch++) {
      float w = wch[hh][ch];
      if (w != 0.f)
        v += pacc[(((size_t)(b * KVH_ + kvh) * NCH + ch) * G_ + g) * D_ + d] * w;
    }
    v *= invL[hh];
    attnB[(size_t)b * (H_ * D_) + j] = v;
    amax = fmaxf(amax, fabsf(v));
  }
#pragma unroll
  for (int off = 32; off; off >>= 1) amax = fmaxf(amax, __shfl_xor(amax, off));
  if ((tid & 63) == 0) rbuf[tid >> 6] = amax;
  __syncthreads();
  if (tid == 0)
    amaxp[b * 8 + sl] = fmaxf(fmaxf(rbuf[0], rbuf[1]), fmaxf(rbuf[2], rbuf[3]));
}

// ---------- quantize attn + build MFMA fragments + asb ----------
__global__ __launch_bounds__(256) void kcomb2(const float* __restrict__ attnB, const float* __restrict__ amaxp,
                                              uint4* __restrict__ frag, float* __restrict__ asb) {
  int gid = blockIdx.x * 256 + threadIdx.x;
  int l = gid & 63, t = gid >> 6;
  int bb = l & 31;
  int k0 = t * 16 + (l >> 5) * 8;
  float amax = 0.f;
#pragma unroll
  for (int sl = 0; sl < 8; sl++) amax = fmaxf(amax, amaxp[bb * 8 + sl]);
  float as = fmaxf(amax, 1e-6f) * (1.f / 127.f);
  float inv = 1.f / as;
  if (gid < 32) asb[gid] = as;
  const float* src = &attnB[(size_t)bb * (H_ * D_) + k0];
  float4 s0 = *(const float4*)src;
  float4 s1 = *(const float4*)(src + 4);
  float v[8];
  v[0] = s0.x; v[1] = s0.y; v[2] = s0.z; v[3] = s0.w;
  v[4] = s1.x; v[5] = s1.y; v[6] = s1.z; v[7] = s1.w;
#pragma unroll
  for (int e = 0; e < 8; e++) {
    float q = rintf(v[e] * inv);
    v[e] = fminf(fmaxf(q, -127.f), 127.f);
  }
  uint4 o;
  o.x = pk2(v[0], v[1]);
  o.y = pk2(v[2], v[3]);
  o.z = pk2(v[4], v[5]);
  o.w = pk2(v[6], v[7]);
  frag[gid] = o;
}

extern "C" void kernel_launch(void* const* d_in, const int* in_sizes, int n_in,
                              void* d_out, int out_size, void* d_ws, size_t ws_size,
                              hipStream_t stream) {
  const int*   hq    = (const int*)d_in[0];
  const float* hs    = (const float*)d_in[1];
  const int*   qkvw  = (const int*)d_in[2];
  const float* qkvws = (const float*)d_in[3];
  const int*   ow    = (const int*)d_in[4];
  const float* owsc  = (const float*)d_in[5];
  const int*   kvc   = (const int*)d_in[6];
  const float* kvs   = (const float*)d_in[7];
  const int*   btab  = (const int*)d_in[8];
  const int*   ctx   = (const int*)d_in[9];
  float* out = (float*)d_out;

  char* ws = (char*)d_ws;
  uint4* xf    = (uint4*)(ws);                 //   262144
  uint4* af    = (uint4*)(ws + 262144);        //   262144
  float* Yp    = (float*)(ws + 524288);        // 12582912
  float* YsT   = (float*)(ws + 13107200);      //   786432
  float* qrope = (float*)(ws + 13893632);      //   524288
  int*   kqf   = (int*)  (ws + 14417920);      //   131072
  int*   vqf   = (int*)  (ws + 14548992);      //   131072
  float* ksf   = (float*)(ws + 14680064);      //     1024
  float* vsf   = (float*)(ws + 14681088);      //     1024
  float* pm    = (float*)(ws + 14686208);      //   131072
  float* pl    = (float*)(ws + 14817280);      //   131072
  float* pacc  = (float*)(ws + 14948352);      // 16777216
  float* attnB = (float*)(ws + 31725568);      //   524288
  float* amaxp = (float*)(ws + 32249856);      //     1024
  float* asb   = (float*)(ws + 32250880);      //      128

  kprep_x<<<64, 256, 0, stream>>>(hq, xf);
  kgemm_mfma<GRPP><<<dim3(RQKV / 128, KS_), 256, 0, stream>>>(qkvw, xf, Yp, RQKV);
  kred<RREP><<<RQKV / 32, 256, 0, stream>>>(Yp, hs, qkvws, YsT, RQKV);
  kpost_qkv<<<dim3(48, 32), 128, 0, stream>>>(YsT, ctx, qrope, kqf, vqf, ksf, vsf);
  kattn<<<dim3(NCH, KVH_, B_), 256, 0, stream>>>(kvc, kvs, btab, ctx, qrope, kqf, ksf, vqf, vsf, pm, pl, pacc);
  kcomb1<<<dim3(8, B_), 256, 0, stream>>>(pm, pl, pacc, attnB, amaxp);
  kcomb2<<<64, 256, 0, stream>>>(attnB, amaxp, af, asb);
  kgemm_mfma<GRPP><<<dim3(HID_ / 128, KS_), 256, 0, stream>>>(ow, af, Yp, HID_);
  kred<RREP><<<HID_ / 32, 256, 0, stream>>>(Yp, asb, owsc, out, HID_);
}

// Round 8
// 161.376 us; speedup vs baseline: 8.8329x; 8.8329x over previous
//
#include <hip/hip_runtime.h>
#include <math.h>

#define B_    32
#define H_    32
#define KVH_  8
#define D_    128
#define HID_  4096
#define TPB_  64
#define MB_   32
#define G_    4
#define RQKV  6144
#define KS_   16
#define NCH   32
#define SCALING 0.08838834764831845f

typedef __attribute__((ext_vector_type(8))) short short8_t;
typedef __attribute__((ext_vector_type(16))) float f32x16;

__device__ __forceinline__ unsigned int pk2(float lo, float hi) {
  return (__float_as_uint(hi) & 0xffff0000u) | (__float_as_uint(lo) >> 16);
}

__device__ __forceinline__ void gl_lds16(const void* g, void* l) {
  __builtin_amdgcn_global_load_lds((const __attribute__((address_space(1))) void*)g,
                                   (__attribute__((address_space(3))) void*)l, 16, 0, 0);
}

// ---------- build X B-fragments from hidden_q (int [32][4096]) ----------
__global__ __launch_bounds__(256) void kprep_x(const int* __restrict__ src, uint4* __restrict__ frag) {
  int gid = blockIdx.x * 256 + threadIdx.x;
  int l = gid & 63, t = gid >> 6;
  int bb = l & 31;
  int k0 = t * 16 + (l >> 5) * 8;
  const int* p = &src[(size_t)bb * HID_ + k0];
  int4 a = *(const int4*)p;
  int4 c = *(const int4*)(p + 4);
  uint4 o;
  o.x = pk2((float)a.x, (float)a.y);
  o.y = pk2((float)a.z, (float)a.w);
  o.z = pk2((float)c.x, (float)c.y);
  o.w = pk2((float)c.z, (float)c.w);
  frag[gid] = o;
}

// ---------- MFMA GEMM with LDS-staged W ----------
__global__ __launch_bounds__(256) void kgemm_mfma(const int* __restrict__ W, const uint4* __restrict__ xf,
                                                  float* __restrict__ Yp, int R) {
  __shared__ __align__(16) int wtile[8192];
  int tid = threadIdx.x;
  int wave = tid >> 6, lane = tid & 63;
  int j0 = blockIdx.x * 128;
  int row = lane & 31, hi = lane >> 5;
  int kbase = blockIdx.y * 256;
  uint4 bw[16];
#pragma unroll
  for (int t = 0; t < 16; t++) bw[t] = xf[(size_t)((kbase >> 4) + t) * 64 + lane];
  f32x16 acc;
#pragma unroll
  for (int i = 0; i < 16; i++) acc[i] = 0.f;
  int ldsrow = wave * 32 + row;
  int rsw = ldsrow & 7;
  for (int ss = 0; ss < 4; ss++) {
#pragma unroll
    for (int n = 0; n < 8; n++) {
      int f = n * 4096 + tid * 16;
      int r = f >> 8;
      int sl = (f >> 4) & 15;
      const int* gsrc = W + (size_t)(j0 + r) * HID_ + kbase + ss * 64 + ((sl ^ (r & 7)) << 2);
      gl_lds16(gsrc, (char*)wtile + f);
    }
    __syncthreads();
#pragma unroll
    for (int t = 0; t < 4; t++) {
      int s0 = 4 * t + 2 * hi;
      int4 wa = *(const int4*)&wtile[ldsrow * 64 + ((s0 ^ rsw) << 2)];
      int4 wb = *(const int4*)&wtile[ldsrow * 64 + (((s0 + 1) ^ rsw) << 2)];
      uint4 aw;
      aw.x = pk2((float)wa.x, (float)wa.y);
      aw.y = pk2((float)wa.z, (float)wa.w);
      aw.z = pk2((float)wb.x, (float)wb.y);
      aw.w = pk2((float)wb.z, (float)wb.w);
      acc = __builtin_amdgcn_mfma_f32_32x32x16_bf16(__builtin_bit_cast(short8_t, aw),
                                                    __builtin_bit_cast(short8_t, bw[ss * 4 + t]),
                                                    acc, 0, 0, 0);
    }
    __syncthreads();
  }
  int jw = j0 + wave * 32;
#pragma unroll
  for (int r = 0; r < 16; r++) {
    int rowout = (r & 3) + 8 * (r >> 2) + 4 * hi;
    Yp[((size_t)blockIdx.y * R + jw + rowout) * 32 + (lane & 31)] = acc[r];
  }
}

// ---------- coalesced reduce over k-slices + LDS transpose ----------
__global__ __launch_bounds__(256) void kred(const float* __restrict__ Yp, const float* __restrict__ sb,
                                            const float* __restrict__ sj, float* __restrict__ outT, int R) {
  int tid = threadIdx.x;
  int j0 = blockIdx.x * 32;
  __shared__ float lds[32 * 33];
  float acc[4] = {0.f, 0.f, 0.f, 0.f};
  for (int ks = 0; ks < KS_; ks++) {
    const float* p = &Yp[(size_t)ks * R * 32 + j0 * 32];
#pragma unroll
    for (int e = 0; e < 4; e++) acc[e] += p[e * 256 + tid];
  }
#pragma unroll
  for (int e = 0; e < 4; e++) {
    int f = e * 256 + tid;
    int jl = f >> 5, b = f & 31;
    lds[b * 33 + jl] = acc[e];
  }
  __syncthreads();
#pragma unroll
  for (int e = 0; e < 4; e++) {
    int f = e * 256 + tid;
    int b = f >> 5, jl = f & 31;
    outT[(size_t)b * R + j0 + jl] = lds[b * 33 + jl] * sb[b] * sj[j0 + jl];
  }
}

// ---------- RoPE + fresh k/v quant ----------
__global__ __launch_bounds__(128) void kpost_qkv(const float* __restrict__ YsT, const int* __restrict__ ctx,
                                                 float* __restrict__ qrope, int* __restrict__ kqf,
                                                 int* __restrict__ vqf, float* __restrict__ ksf,
                                                 float* __restrict__ vsf) {
  int r = blockIdx.x;
  int b = blockIdx.y;
  int d = threadIdx.x;
  float v = YsT[(size_t)b * RQKV + r * 128 + d];
  __shared__ float x[128];
  __shared__ float red[2];
  x[d] = v;
  __syncthreads();
  int pos = ctx[b];
  float val;
  if (r < 40) {
    int i = d & 63;
    float f = powf(10000.f, -(float)i * (1.f / 64.f));
    float ang = (float)pos * f;
    float sv, cv;
    sincosf(ang, &sv, &cv);
    float xa = x[i], xb = x[i + 64];
    val = (d < 64) ? (xa * cv - xb * sv) : (xb * cv + xa * sv);
  } else {
    val = v;
  }
  if (r < 32) { qrope[((size_t)b * H_ + r) * D_ + d] = val; return; }
  float a = fabsf(val);
#pragma unroll
  for (int off = 32; off; off >>= 1) a = fmaxf(a, __shfl_xor(a, off));
  if ((d & 63) == 0) red[d >> 6] = a;
  __syncthreads();
  float mx = fmaxf(red[0], red[1]);
  float sc = fmaxf(mx, 1e-6f) * (1.f / 127.f);
  float qv = rintf(val / sc);
  qv = fminf(fmaxf(qv, -127.f), 127.f);
  int kvh = (r - 32) & 7;
  if (r < 40) {
    kqf[((size_t)b * KVH_ + kvh) * D_ + d] = (int)qv;
    if (d == 0) ksf[b * KVH_ + kvh] = sc;
  } else {
    vqf[((size_t)b * KVH_ + kvh) * D_ + d] = (int)qv;
    if (d == 0) vsf[b * KVH_ + kvh] = sc;
  }
}

// ---------- attention: direct-global K/V, high-ILP PV, 64-token block per WG ----------
__global__ __launch_bounds__(256) void kattn(const int* __restrict__ kvc, const float* __restrict__ kvs,
                                             const int* __restrict__ btab, const int* __restrict__ ctx,
                                             const float* __restrict__ qrope, const int* __restrict__ kqf,
                                             const float* __restrict__ ksf,
                                             const int* __restrict__ vqf, const float* __restrict__ vsf,
                                             float* __restrict__ pm, float* __restrict__ pl,
                                             float* __restrict__ pacc) {
  int cb = blockIdx.x, kvh = blockIdx.y, b = blockIdx.z;
  int tid = threadIdx.x;
  int pos = ctx[b];
  size_t pbase = ((size_t)(b * KVH_ + kvh) * NCH + cb) * G_;
  if (cb * 64 > pos) {
    if (tid < 4) { pm[pbase + tid] = -1e30f; pl[pbase + tid] = 0.f; }
    return;
  }
  __shared__ __align__(16) float qlds[512];     // XOR-swizzled: w ^ (((w>>5)&3)<<2)
  __shared__ float sls[4][64];
  __shared__ __align__(16) float pls4[64][4];   // [token][g] - b128 broadcast in PV
  __shared__ float pvred[8][516];               // padded: conflict-free reduce reads
  int blk = btab[b * MB_ + cb];
  int freshT = pos - cb * 64;                   // in [0,64) iff fresh token in this block
  const int* kpan = &kvc[(((size_t)(blk * 2 + 0) * KVH_ + kvh) * TPB_) * D_];
  const int* vpan = &kvc[(((size_t)(blk * 2 + 1) * KVH_ + kvh) * TPB_) * D_];

  for (int i = tid; i < 512; i += 256) {
    int sw = i ^ (((i >> 5) & 3) << 2);
    qlds[sw] = qrope[((size_t)b * H_ + kvh * G_) * D_ + i];
  }
  __syncthreads();

  // ---- phase 1: QK^T, 4 lanes per token, K direct from global (8x16B in flight/lane) ----
  {
    int t = tid >> 2, c = tid & 3;
    const int* krow = kpan + t * 128 + c * 32;
    float kv[32];
#pragma unroll
    for (int i = 0; i < 8; i++) {
      int4 k4 = *(const int4*)&krow[i * 4];
      kv[i * 4 + 0] = (float)k4.x;
      kv[i * 4 + 1] = (float)k4.y;
      kv[i * 4 + 2] = (float)k4.z;
      kv[i * 4 + 3] = (float)k4.w;
    }
    float ksc = kvs[((size_t)(blk * 2 + 0) * KVH_ + kvh) * TPB_ + t] * SCALING;
#pragma unroll
    for (int g = 0; g < 4; g++) {
      int base = g * 128 + c * 32;
      float dot = 0.f;
#pragma unroll
      for (int i = 0; i < 8; i++) {
        float4 q4 = *(const float4*)&qlds[(base + i * 4) ^ (c << 2)];
        dot += kv[i * 4 + 0] * q4.x + kv[i * 4 + 1] * q4.y +
               kv[i * 4 + 2] * q4.z + kv[i * 4 + 3] * q4.w;
      }
      dot += __shfl_xor(dot, 1);
      dot += __shfl_xor(dot, 2);
      if (c == 0) sls[g][t] = dot * ksc;
    }
  }
  __syncthreads();

  // ---- phase 2: softmax, one wave per head; fresh score computed in-wave ----
  {
    int g = tid >> 6, t = tid & 63;
    int s = cb * 64 + t;
    float sc = sls[g][t];
    if (freshT >= 0 && freshT < 64) {
      const int* kk = &kqf[(size_t)(b * KVH_ + kvh) * D_];
      float q1 = qlds[(g * 128 + t) ^ (((t >> 5) & 3) << 2)];
      float q2 = qlds[(g * 128 + 64 + t) ^ ((((t >> 5) + 2) & 3) << 2)];
      float dotf = q1 * (float)kk[t] + q2 * (float)kk[t + 64];
#pragma unroll
      for (int off = 32; off; off >>= 1) dotf += __shfl_xor(dotf, off);
      if (t == freshT) sc = dotf * ksf[b * KVH_ + kvh] * SCALING;
    }
    if (s > pos) sc = -1e30f;
    float m = sc;
#pragma unroll
    for (int off = 32; off; off >>= 1) m = fmaxf(m, __shfl_xor(m, off));
    float p = (s <= pos) ? expf(sc - m) : 0.f;
    float l = p;
#pragma unroll
    for (int off = 32; off; off >>= 1) l += __shfl_xor(l, off);
    if (t == 0) { pm[pbase + g] = m; pl[pbase + g] = l; }
    float vsc = (s == pos) ? vsf[b * KVH_ + kvh]
                           : kvs[((size_t)(blk * 2 + 1) * KVH_ + kvh) * TPB_ + t];
    pls4[t][g] = p * vsc;
  }
  __syncthreads();

  // ---- phase 3: PV, thread = (d-quad, token-group): 8 independent 16B V loads ----
  {
    int dq = tid & 31, tg = tid >> 5;
    const int* vb = vpan + dq * 4;
    const int* vfr = vqf + (size_t)(b * KVH_ + kvh) * D_ + dq * 4;
    float a00 = 0.f, a01 = 0.f, a02 = 0.f, a03 = 0.f;
    float a10 = 0.f, a11 = 0.f, a12 = 0.f, a13 = 0.f;
    float a20 = 0.f, a21 = 0.f, a22 = 0.f, a23 = 0.f;
    float a30 = 0.f, a31 = 0.f, a32 = 0.f, a33 = 0.f;
#pragma unroll
    for (int j = 0; j < 8; j++) {
      int tt = tg * 8 + j;
      const int* vr = (tt == freshT) ? vfr : (vb + tt * 128);
      int4 v4 = *(const int4*)vr;
      float4 pp = *(const float4*)&pls4[tt][0];
      float v0 = (float)v4.x, v1 = (float)v4.y, v2 = (float)v4.z, v3 = (float)v4.w;
      a00 = fmaf(pp.x, v0, a00); a01 = fmaf(pp.x, v1, a01); a02 = fmaf(pp.x, v2, a02); a03 = fmaf(pp.x, v3, a03);
      a10 = fmaf(pp.y, v0, a10); a11 = fmaf(pp.y, v1, a11); a12 = fmaf(pp.y, v2, a12); a13 = fmaf(pp.y, v3, a13);
      a20 = fmaf(pp.z, v0, a20); a21 = fmaf(pp.z, v1, a21); a22 = fmaf(pp.z, v2, a22); a23 = fmaf(pp.z, v3, a23);
      a30 = fmaf(pp.w, v0, a30); a31 = fmaf(pp.w, v1, a31); a32 = fmaf(pp.w, v2, a32); a33 = fmaf(pp.w, v3, a33);
    }
    *(float4*)&pvred[tg][0 * 128 + dq * 4] = make_float4(a00, a01, a02, a03);
    *(float4*)&pvred[tg][1 * 128 + dq * 4] = make_float4(a10, a11, a12, a13);
    *(float4*)&pvred[tg][2 * 128 + dq * 4] = make_float4(a20, a21, a22, a23);
    *(float4*)&pvred[tg][3 * 128 + dq * 4] = make_float4(a30, a31, a32, a33);
  }
  __syncthreads();

  // ---- phase 4: 8-way tree reduce (conflict-free: bank = (4*tg + idx) % 32) ----
  {
#pragma unroll
    for (int rr = 0; rr < 2; rr++) {
      int idx = rr * 256 + tid;
      float s = pvred[0][idx] + pvred[1][idx] + pvred[2][idx] + pvred[3][idx] +
                pvred[4][idx] + pvred[5][idx] + pvred[6][idx] + pvred[7][idx];
      pacc[pbase * D_ + idx] = s;
    }
  }
}

// ---------- combine chunks -> attnB[b][j] + partial amax ----------
__global__ __launch_bounds__(256) void kcomb1(const float* __restrict__ pm, const float* __restrict__ pl,
                                              const float* __restrict__ pacc, float* __restrict__ attnB,
                                              float* __restrict__ amaxp) {
  int sl = blockIdx.x, b = blockIdx.y;
  int tid = threadIdx.x;
  __shared__ float wch[32][32];
  __shared__ float invL[32];
  __shared__ float rbuf[4];
  if (tid < 32) {
    int kvh = tid >> 2, g = tid & 3;
    float M = -1e30f;
    float m[NCH];
#pragma unroll
    for (int ch = 0; ch < NCH; ch++) {
      m[ch] = pm[((size_t)(b * KVH_ + kvh) * NCH + ch) * G_ + g];
      M = fmaxf(M, m[ch]);
    }
    float L = 0.f;
#pragma unroll
    for (int ch = 0; ch < NCH; ch++) {
      float w = expf(m[ch] - M);
      wch[tid][ch] = w;
      L += pl[((size_t)(b * KVH_ + kvh) * NCH + ch) * G_ + g] * w;
    }
    invL[tid] = 1.f / L;
  }
  __syncthreads();
  float amax = 0.f;
#pragma unroll
  for (int rep = 0; rep < 2; rep++) {
    int j = sl * 512 + rep * 256 + tid;
    int h = j >> 7, d = j & 127;
    int kvh = h >> 2, g = h & 3;
    int hh = kvh * 4 + g;
    float v = 0.f;
#pragma unroll 8
    for (int ch = 0; ch < NCH; ch++) {
      float w = wch[hh][ch];
      if (w != 0.f)
        v += pacc[(((size_t)(b * KVH_ + kvh) * NCH + ch) * G_ + g) * D_ + d] * w;
    }
    v *= invL[hh];
    attnB[(size_t)b * (H_ * D_) + j] = v;
    amax = fmaxf(amax, fabsf(v));
  }
#pragma unroll
  for (int off = 32; off; off >>= 1) amax = fmaxf(amax, __shfl_xor(amax, off));
  if ((tid & 63) == 0) rbuf[tid >> 6] = amax;
  __syncthreads();
  if (tid == 0)
    amaxp[b * 8 + sl] = fmaxf(fmaxf(rbuf[0], rbuf[1]), fmaxf(rbuf[2], rbuf[3]));
}

// ---------- quantize attn + build MFMA fragments + asb ----------
__global__ __launch_bounds__(256) void kcomb2(const float* __restrict__ attnB, const float* __restrict__ amaxp,
                                              uint4* __restrict__ frag, float* __restrict__ asb) {
  int gid = blockIdx.x * 256 + threadIdx.x;
  int l = gid & 63, t = gid >> 6;
  int bb = l & 31;
  int k0 = t * 16 + (l >> 5) * 8;
  float amax = 0.f;
#pragma unroll
  for (int sl = 0; sl < 8; sl++) amax = fmaxf(amax, amaxp[bb * 8 + sl]);
  float as = fmaxf(amax, 1e-6f) * (1.f / 127.f);
  float inv = 1.f / as;
  if (gid < 32) asb[gid] = as;
  const float* src = &attnB[(size_t)bb * (H_ * D_) + k0];
  float4 s0 = *(const float4*)src;
  float4 s1 = *(const float4*)(src + 4);
  float v[8];
  v[0] = s0.x; v[1] = s0.y; v[2] = s0.z; v[3] = s0.w;
  v[4] = s1.x; v[5] = s1.y; v[6] = s1.z; v[7] = s1.w;
#pragma unroll
  for (int e = 0; e < 8; e++) {
    float q = rintf(v[e] * inv);
    v[e] = fminf(fmaxf(q, -127.f), 127.f);
  }
  uint4 o;
  o.x = pk2(v[0], v[1]);
  o.y = pk2(v[2], v[3]);
  o.z = pk2(v[4], v[5]);
  o.w = pk2(v[6], v[7]);
  frag[gid] = o;
}

extern "C" void kernel_launch(void* const* d_in, const int* in_sizes, int n_in,
                              void* d_out, int out_size, void* d_ws, size_t ws_size,
                              hipStream_t stream) {
  const int*   hq    = (const int*)d_in[0];
  const float* hs    = (const float*)d_in[1];
  const int*   qkvw  = (const int*)d_in[2];
  const float* qkvws = (const float*)d_in[3];
  const int*   ow    = (const int*)d_in[4];
  const float* owsc  = (const float*)d_in[5];
  const int*   kvc   = (const int*)d_in[6];
  const float* kvs   = (const float*)d_in[7];
  const int*   btab  = (const int*)d_in[8];
  const int*   ctx   = (const int*)d_in[9];
  float* out = (float*)d_out;

  char* ws = (char*)d_ws;
  uint4* xf    = (uint4*)(ws);                 //   262144
  uint4* af    = (uint4*)(ws + 262144);        //   262144
  float* Yp    = (float*)(ws + 524288);        // 12582912
  float* YsT   = (float*)(ws + 13107200);      //   786432
  float* qrope = (float*)(ws + 13893632);      //   524288
  int*   kqf   = (int*)  (ws + 14417920);      //   131072
  int*   vqf   = (int*)  (ws + 14548992);      //   131072
  float* ksf   = (float*)(ws + 14680064);      //     1024
  float* vsf   = (float*)(ws + 14681088);      //     1024
  float* pm    = (float*)(ws + 14686208);      //   131072
  float* pl    = (float*)(ws + 14817280);      //   131072
  float* pacc  = (float*)(ws + 14948352);      // 16777216
  float* attnB = (float*)(ws + 31725568);      //   524288
  float* amaxp = (float*)(ws + 32249856);      //     1024
  float* asb   = (float*)(ws + 32250880);      //      128

  kprep_x<<<64, 256, 0, stream>>>(hq, xf);
  kgemm_mfma<<<dim3(RQKV / 128, KS_), 256, 0, stream>>>(qkvw, xf, Yp, RQKV);
  kred<<<RQKV / 32, 256, 0, stream>>>(Yp, hs, qkvws, YsT, RQKV);
  kpost_qkv<<<dim3(48, 32), 128, 0, stream>>>(YsT, ctx, qrope, kqf, vqf, ksf, vsf);
  kattn<<<dim3(NCH, KVH_, B_), 256, 0, stream>>>(kvc, kvs, btab, ctx, qrope, kqf, ksf, vqf, vsf, pm, pl, pacc);
  kcomb1<<<dim3(8, B_), 256, 0, stream>>>(pm, pl, pacc, attnB, amaxp);
  kcomb2<<<64, 256, 0, stream>>>(attnB, amaxp, af, asb);
  kgemm_mfma<<<dim3(HID_ / 128, KS_), 256, 0, stream>>>(ow, af, Yp, HID_);
  kred<<<HID_ / 32, 256, 0, stream>>>(Yp, asb, owsc, out, HID_);
}